// Round 14
// baseline (4601.756 us; speedup 1.0000x reference)
//
#include <hip/hip_runtime.h>
#include <hip/hip_bf16.h>

#define BB 4
#define NN 8192
#define CC 64
#define SS 2048
#define GG 32
#define C2V 128
#define HHV 512

typedef unsigned long long u64;
typedef unsigned int u32;

// ---------------------------------------------------------------- transpose fea (B,C,N)->(B,N,C)
__global__ void k_transpose_fea(const float* __restrict__ in, float* __restrict__ out) {
  __shared__ float tile[32][33];
  const int b = blockIdx.z;
  const int n0 = blockIdx.x * 32, c0 = blockIdx.y * 32;
  const int tx = threadIdx.x, ty = threadIdx.y;
  const float* src = in + (size_t)b * CC * NN;
#pragma unroll
  for (int i = 0; i < 32; i += 8)
    tile[ty + i][tx] = src[(size_t)(c0 + ty + i) * NN + n0 + tx];
  __syncthreads();
  float* dst = out + (size_t)b * NN * CC;
#pragma unroll
  for (int i = 0; i < 32; i += 8)
    dst[(size_t)(n0 + ty + i) * CC + c0 + tx] = tile[tx][ty + i];
}

// ---------------------------------------------------------------- FPS (v8: AGPR-parked coords)
// FROZEN at r13: per-active-CU VALU ~98% -> at this structure's issue floor.
__global__ __launch_bounds__(1024, 4) void k_fps(const float* __restrict__ pc, int* __restrict__ fps_idx) {
#pragma clang fp contract(off)
  __shared__ float lx[NN], ly[NN], lz[NN];
  __shared__ int sIdx[SS];
  __shared__ u64 sK[2][16];
  const int b = blockIdx.x, tid = threadIdx.x;
  const int lane = tid & 63, wid = tid >> 6;
  const float* pb = pc + (size_t)b * 3 * NN;

  const float4* gx = (const float4*)pb;
  const float4* gy = (const float4*)(pb + NN);
  const float4* gz = (const float4*)(pb + 2 * NN);
  float4 vXa = gx[tid], vXb = gx[tid + 1024];
  float4 vYa = gy[tid], vYb = gy[tid + 1024];
  float4 vZa = gz[tid], vZb = gz[tid + 1024];
  {
    float4* sx = (float4*)lx; float4* sy = (float4*)ly; float4* sz = (float4*)lz;
    sx[tid] = vXa; sx[tid + 1024] = vXb;
    sy[tid] = vYa; sy[tid + 1024] = vYb;
    sz[tid] = vZa; sz[tid + 1024] = vZb;
  }
  float aXax, aXay, aXaz, aXaw, aXbx, aXby, aXbz, aXbw;
  float aYax, aYay, aYaz, aYaw, aYbx, aYby, aYbz, aYbw;
  float aZax, aZay, aZaz, aZaw, aZbx, aZby, aZbz, aZbw;
#define PARK(A, V) asm volatile("v_accvgpr_write_b32 %0, %1" : "=a"(A) : "v"(V));
  PARK(aXax, vXa.x) PARK(aXay, vXa.y) PARK(aXaz, vXa.z) PARK(aXaw, vXa.w)
  PARK(aXbx, vXb.x) PARK(aXby, vXb.y) PARK(aXbz, vXb.z) PARK(aXbw, vXb.w)
  PARK(aYax, vYa.x) PARK(aYay, vYa.y) PARK(aYaz, vYa.z) PARK(aYaw, vYa.w)
  PARK(aYbx, vYb.x) PARK(aYby, vYb.y) PARK(aYbz, vYb.z) PARK(aYbw, vYb.w)
  PARK(aZax, vZa.x) PARK(aZay, vZa.y) PARK(aZaz, vZa.z) PARK(aZaw, vZa.w)
  PARK(aZbx, vZb.x) PARK(aZby, vZb.y) PARK(aZbz, vZb.z) PARK(aZbw, vZb.w)
#undef PARK
  if (tid < 32) ((u64*)sK)[tid] = 0ull;
  if (tid == 0) sK[0][0] = ~0ull;   // step-0 winner: idx 0
  __syncthreads();

  const u32 ibase = (u32)(wid * 256 + lane * 4);
  float4 D0 = make_float4(1e20f, 1e20f, 1e20f, 1e20f);
  float4 D1 = D0;

#define DPPK64(K, CTL) { \
      u32 lo = (u32)(K), hi = (u32)((K) >> 32); \
      u32 lo2 = (u32)__builtin_amdgcn_update_dpp(0, (int)lo, CTL, 0xf, 0xf, false); \
      u32 hi2 = (u32)__builtin_amdgcn_update_dpp(0, (int)hi, CTL, 0xf, 0xf, false); \
      u64 k2 = ((u64)hi2 << 32) | (u64)lo2; if (k2 > (K)) (K) = k2; }
#define RMAXF(V, CTL) { \
      float t_ = __int_as_float(__builtin_amdgcn_update_dpp(0, __float_as_int(V), CTL, 0xf, 0xf, false)); \
      (V) = fmaxf((V), t_); }
#define RMINU(V, CTL) { \
      u32 t_ = (u32)__builtin_amdgcn_update_dpp(0, (int)(V), CTL, 0xf, 0xf, false); \
      (V) = min((V), t_); }
#define FETCH(V, A) asm volatile("v_accvgpr_read_b32 %0, %1" : "=v"(V) : "a"(A));

  for (int k = 0; k < SS; ++k) {
    const int p = k & 1, pn = p ^ 1;
    u64 kk = sK[p][lane & 15];
    float xax, xay, xaz, xaw, xbx, xby, xbz, xbw;
    float yax, yay, yaz, yaw, ybx, yby, ybz, ybw;
    float zax, zay, zaz, zaw, zbx, zby, zbz, zbw;
    FETCH(xax, aXax) FETCH(xay, aXay) FETCH(xaz, aXaz) FETCH(xaw, aXaw)
    FETCH(xbx, aXbx) FETCH(xby, aXby) FETCH(xbz, aXbz) FETCH(xbw, aXbw)
    FETCH(yax, aYax) FETCH(yay, aYay) FETCH(yaz, aYaz) FETCH(yaw, aYaw)
    FETCH(ybx, aYbx) FETCH(yby, aYby) FETCH(ybz, aYbz) FETCH(ybw, aYbw)
    FETCH(zax, aZax) FETCH(zay, aZay) FETCH(zaz, aZaz) FETCH(zaw, aZaw)
    FETCH(zbx, aZbx) FETCH(zby, aZby) FETCH(zbz, aZbz) FETCH(zbw, aZbw)
    DPPK64(kk, 0x121) DPPK64(kk, 0x122) DPPK64(kk, 0x124) DPPK64(kk, 0x128)
    const u32 idx = 0xFFFFFFFFu - (u32)kk;
    if (tid == 0) sIdx[k] = (int)idx;
    const float cx = lx[idx], cy = ly[idx], cz = lz[idx];

#define UPDC(XX, YY, ZZ, DD) { \
      float dx_ = (XX) - cx, dy_ = (YY) - cy, dz_ = (ZZ) - cz; \
      float t0_ = dx_ * dx_, t1_ = dy_ * dy_, t2_ = dz_ * dz_; \
      float s_ = (t0_ + t1_) + t2_; \
      (DD) = fminf((DD), s_); }
    UPDC(xax, yax, zax, D0.x) UPDC(xay, yay, zay, D0.y)
    UPDC(xaz, yaz, zaz, D0.z) UPDC(xaw, yaw, zaw, D0.w)
    UPDC(xbx, ybx, zbx, D1.x) UPDC(xby, yby, zby, D1.y)
    UPDC(xbz, ybz, zbz, D1.z) UPDC(xbw, ybw, zbw, D1.w)
#undef UPDC

    float m2 = fmaxf(fmaxf(fmaxf(D0.x, D0.y), fmaxf(D0.z, D0.w)),
                     fmaxf(fmaxf(D1.x, D1.y), fmaxf(D1.z, D1.w)));
    RMAXF(m2, 0x121) RMAXF(m2, 0x122) RMAXF(m2, 0x124) RMAXF(m2, 0x128)
    m2 = fmaxf(m2, __shfl_xor(m2, 16, 64));
    m2 = fmaxf(m2, __shfl_xor(m2, 32, 64));

    float s = sqrtf(m2);
    u32 sbits = __float_as_uint(s);
    float spred = __uint_as_float(sbits - 1u);
    double M = ((double)spred + (double)s) * 0.5;
    double L = M * M;
    if (sbits & 1u) L = __longlong_as_double(__double_as_longlong(L) + 1ll);
    float Lf = (float)L;
    if ((double)Lf < L) Lf = __uint_as_float(__float_as_uint(Lf) + 1u);

    u32 enc = 0xFFFFFFFFu;
    {
      int off = -1;
      if (D1.w >= Lf) off = 4096 + 3;
      if (D1.z >= Lf) off = 4096 + 2;
      if (D1.y >= Lf) off = 4096 + 1;
      if (D1.x >= Lf) off = 4096 + 0;
      if (D0.w >= Lf) off = 3;
      if (D0.z >= Lf) off = 2;
      if (D0.y >= Lf) off = 1;
      if (D0.x >= Lf) off = 0;
      if (off >= 0) enc = ibase + (u32)off;
    }
    RMINU(enc, 0x121) RMINU(enc, 0x122) RMINU(enc, 0x124) RMINU(enc, 0x128)
    enc = min(enc, (u32)__shfl_xor((int)enc, 16, 64));
    enc = min(enc, (u32)__shfl_xor((int)enc, 32, 64));

    if (lane == 0)
      sK[pn][wid] = (((u64)sbits) << 32) | (u64)(0xFFFFFFFFu - enc);
    __syncthreads();
  }
#undef DPPK64
#undef RMAXF
#undef RMINU
#undef FETCH
  fps_idx[b * SS + tid] = sIdx[tid];
  fps_idx[b * SS + 1024 + tid] = sIdx[1024 + tid];
}

// ---------------------------------------------------------------- gather new_coor + out0
__global__ void k_gather(const float* __restrict__ pc, const int* __restrict__ fps_idx,
                         float* __restrict__ ncoor, float* __restrict__ out0) {
  int t = blockIdx.x * 256 + threadIdx.x;
  if (t >= BB * SS) return;
  int b = t / SS, s = t % SS;
  int id = fps_idx[t];
  const float* base = pc + (size_t)b * 3 * NN;
  float x = base[id], y = base[NN + id], z = base[2 * NN + id];
  ncoor[(size_t)t * 3] = x; ncoor[(size_t)t * 3 + 1] = y; ncoor[(size_t)t * 3 + 2] = z;
  size_t o = (size_t)b * 3 * SS + s;
  out0[o] = x; out0[o + SS] = y; out0[o + 2 * SS] = z;
}

// ---------------------------------------------------------------- kNN, 2 queries per block
// Shares the candidate-point load stream between 2 queries (halves candp
// traffic). Distance math bit-identical to the verified r5+ chain: FMA-chain
// dot (np einsum under gcc contract=fast), contract-off materialized-squares
// norms, d = ((-2*dot)+qn)+pn. Selection logic per query unchanged.
__global__ __launch_bounds__(256) void k_knn(const float* __restrict__ candp,
                                             const float* __restrict__ newc,
                                             int mode, int ncand, float r2,
                                             int* __restrict__ gidx) {
  __shared__ float cd[2][2048];
  __shared__ int ci[2][2048];
  __shared__ int hist[2][64];
  __shared__ int cnt[2], oc[2], binT[2], mlow[2];
  const int q0 = blockIdx.x * 2, tid = threadIdx.x;
  const int b = q0 / SS;
  if (tid == 0) { cnt[0] = 0; cnt[1] = 0; oc[0] = 0; oc[1] = 0; }
  if (tid < 64) hist[0][tid] = 0;
  else if (tid < 128) hist[1][tid - 64] = 0;
  __syncthreads();
  const float qx0 = newc[(size_t)q0 * 3], qy0 = newc[(size_t)q0 * 3 + 1], qz0 = newc[(size_t)q0 * 3 + 2];
  const float qx1 = newc[(size_t)(q0 + 1) * 3], qy1 = newc[(size_t)(q0 + 1) * 3 + 1], qz1 = newc[(size_t)(q0 + 1) * 3 + 2];
  float qn0, qn1;
  {
#pragma clang fp contract(off)
    qn0 = (qx0 * qx0 + qy0 * qy0) + qz0 * qz0;
    qn1 = (qx1 * qx1 + qy1 * qy1) + qz1 * qz1;
  }
  const float sc = 64.0f / r2;
  const float* base = (mode == 0) ? candp + (size_t)b * 3 * NN : candp + (size_t)b * SS * 3;
  for (int i = tid; i < ncand; i += 256) {
    float x, y, z;
    if (mode == 0) { x = base[i]; y = base[NN + i]; z = base[2 * NN + i]; }
    else { x = base[3 * i]; y = base[3 * i + 1]; z = base[3 * i + 2]; }
    {
      float dot = fmaf(qz0, z, fmaf(qy0, y, qx0 * x));
      float d;
      {
#pragma clang fp contract(off)
        float pn = (x * x + y * y) + z * z;
        d = ((-2.0f * dot) + qn0) + pn;
      }
      if (d <= r2) {
        int pp = atomicAdd(&cnt[0], 1);
        if (pp < 2048) { cd[0][pp] = d; ci[0][pp] = i; }
        float db = (d > 0.0f) ? d : 0.0f;
        atomicAdd(&hist[0][min(63, (int)(db * sc))], 1);
      }
    }
    {
      float dot = fmaf(qz1, z, fmaf(qy1, y, qx1 * x));
      float d;
      {
#pragma clang fp contract(off)
        float pn = (x * x + y * y) + z * z;
        d = ((-2.0f * dot) + qn1) + pn;
      }
      if (d <= r2) {
        int pp = atomicAdd(&cnt[1], 1);
        if (pp < 2048) { cd[1][pp] = d; ci[1][pp] = i; }
        float db = (d > 0.0f) ? d : 0.0f;
        atomicAdd(&hist[1][min(63, (int)(db * sc))], 1);
      }
    }
  }
  __syncthreads();
  if (tid == 0) {
#pragma unroll
    for (int jq = 0; jq < 2; ++jq) {
      const int M = min(cnt[jq], 2048);
      if (M > 32) {
        int c = 0, t = 0;
        for (t = 0; t < 64; ++t) { if (c + hist[jq][t] >= 32) break; c += hist[jq][t]; }
        binT[jq] = t; mlow[jq] = c;
      } else binT[jq] = -1;
    }
  }
  __syncthreads();
  for (int jq = 0; jq < 2; ++jq) {
    const int M = min(cnt[jq], 2048);
    int* out = gidx + (size_t)(q0 + jq) * 32;
    if (binT[jq] < 0) {
      for (int j = tid; j < M; j += 256) out[atomicAdd(&oc[jq], 1)] = ci[jq][j];
      __syncthreads();
      if (tid == 0 && M < 32) {
        float bd = 1e30f; int bx = 0x7FFFFFFF;
        for (int j = 0; j < M; ++j)
          if (cd[jq][j] < bd || (cd[jq][j] == bd && ci[jq][j] < bx)) { bd = cd[jq][j]; bx = ci[jq][j]; }
        for (int j = M; j < 32; ++j) out[j] = bx;
      }
    } else {
      const int bt = binT[jq], m = mlow[jq];
      for (int j = tid; j < M; j += 256) {
        float dbj = (cd[jq][j] > 0.0f) ? cd[jq][j] : 0.0f;
        int bin = min(63, (int)(dbj * sc));
        if (bin < bt) out[atomicAdd(&oc[jq], 1)] = ci[jq][j];
        else if (bin == bt) {
          int r = 0; const float dj = cd[jq][j]; const int ij = ci[jq][j];
          for (int kk = 0; kk < M; ++kk) {
            float dbk = (cd[jq][kk] > 0.0f) ? cd[jq][kk] : 0.0f;
            if (min(63, (int)(dbk * sc)) == bt &&
                (cd[jq][kk] < dj || (cd[jq][kk] == dj && ci[jq][kk] < ij))) ++r;
          }
          if (m + r < 32) out[m + r] = ci[jq][j];
        }
      }
    }
    __syncthreads();
  }
}

// ---------------------------------------------------------------- grouped MLP + max  (out 128 ch)
// e-chunked: neighbors processed in 2 chunks of 16 -> g4 LDS halves
// (FDIM=128: 33.8->16.9 KB) -> ~2x blocks/CU to hide the random-row gather
// latency. Max over chunks is exact; per-(row,d,e) dot-product accumulation
// order unchanged. Weight reads double but are L1/L2-hot broadcast.
template <int FDIM>
__global__ __launch_bounds__(256) void k_group_mlp(
    const float* __restrict__ fea, const int* __restrict__ gidx,
    const float* __restrict__ newc, const float* __restrict__ candp,
    int mode, int ncand, float radius,
    const float* __restrict__ wp, float* __restrict__ outf) {
  constexpr int CP4 = FDIM + 4;     // padded cols (67->68, 131->132)
  constexpr int NC4 = CP4 / 4;
  __shared__ float4 g4[2][16][NC4];
  __shared__ int sidx[2][32];
  __shared__ float sq[2][3];
  __shared__ float pf[2][4][128];
  const int tid = threadIdx.x;
  const int rs = tid >> 7, tl = tid & 127;
  const int dt = tl & 31, et = tl >> 5;   // 32 d-threads x 4 e-threads
  const int d0 = dt * 4, e0 = et * 4;     // 4 d, 4 e each (16 e per chunk)
  const int row0 = blockIdx.x * 4;
  for (int rp = 0; rp < 4; rp += 2) {
    const int row = row0 + rp + rs;
    if (tl < 32) sidx[rs][tl] = gidx[(size_t)row * 32 + tl];
    if (tl < 3) sq[rs][tl] = newc[(size_t)row * 3 + tl];
    __syncthreads();
    const int bb2 = row / SS;
    const float* fb = fea + (size_t)bb2 * ncand * FDIM;
    const float* cb = (mode == 0) ? candp + (size_t)bb2 * 3 * NN
                                  : candp + (size_t)bb2 * SS * 3;
    float* gf = (float*)&g4[rs][0][0];
    const float4* w4 = (const float4*)wp;
    float rmax[4];
#pragma unroll
    for (int i = 0; i < 4; ++i) rmax[i] = -1e30f;
    for (int ec = 0; ec < 2; ++ec) {
      // stage chunk ec (16 neighbors)
      for (int qq = tl; qq < 16 * CP4; qq += 128) {
        int e = qq / CP4, c = qq - e * CP4;
        int id = sidx[rs][ec * 16 + e];
        float v;
        if (c < FDIM) v = fb[(size_t)id * FDIM + c];
        else if (c < FDIM + 3) {
          int comp = c - FDIM;
          float pcv = (mode == 0) ? cb[(size_t)comp * NN + id] : cb[(size_t)id * 3 + comp];
          v = (pcv - sq[rs][comp]) / radius;
        } else v = 0.0f;
        gf[qq] = v;
      }
      __syncthreads();
      float acc[4][4];
#pragma unroll
      for (int i = 0; i < 4; ++i)
#pragma unroll
        for (int j = 0; j < 4; ++j) acc[i][j] = 0.0f;
      for (int c4 = 0; c4 < NC4; ++c4) {
        float4 wv[4], gv[4];
#pragma unroll
        for (int i = 0; i < 4; ++i) wv[i] = w4[(size_t)(d0 + i) * NC4 + c4];
#pragma unroll
        for (int j = 0; j < 4; ++j) gv[j] = g4[rs][e0 + j][c4];
#pragma unroll
        for (int i = 0; i < 4; ++i)
#pragma unroll
          for (int j = 0; j < 4; ++j) {
            acc[i][j] += wv[i].x * gv[j].x;
            acc[i][j] += wv[i].y * gv[j].y;
            acc[i][j] += wv[i].z * gv[j].z;
            acc[i][j] += wv[i].w * gv[j].w;
          }
      }
#pragma unroll
      for (int i = 0; i < 4; ++i)
#pragma unroll
        for (int j = 0; j < 4; ++j) rmax[i] = fmaxf(rmax[i], acc[i][j]);
      __syncthreads();  // g4 reused next chunk
    }
#pragma unroll
    for (int i = 0; i < 4; ++i) pf[rs][et][d0 + i] = rmax[i];
    __syncthreads();
    {
      const int d = tid & 127, r2s = tid >> 7;
      const int rowW = row0 + rp + r2s;
      float m = fmaxf(fmaxf(pf[r2s][0][d], pf[r2s][1][d]),
                      fmaxf(pf[r2s][2][d], pf[r2s][3][d]));
      outf[(size_t)rowW * 128 + d] = fmaxf(m, 0.0f);
    }
    __syncthreads();
  }
}

// ---------------------------------------------------------------- dense GEMM: Out = relu(A(M,K) * W(N,K)^T [+ Id])
template <bool RESID>
__global__ __launch_bounds__(256) void k_dense(
    const float* __restrict__ A, const float* __restrict__ W,
    const float* __restrict__ Id, float* __restrict__ Out,
    int K, int Ntot) {
  __shared__ float4 sa[64][17], sb[64][17];
  const int m0 = blockIdx.x * 64, n0 = blockIdx.y * 64;
  const int tid = threadIdx.x;
  const int mt = tid & 15, nt = tid >> 4;
  float acc[4][4];
#pragma unroll
  for (int i = 0; i < 4; ++i)
#pragma unroll
    for (int j = 0; j < 4; ++j) acc[i][j] = 0.0f;
  for (int kc = 0; kc < K; kc += 64) {
    for (int q2 = tid; q2 < 2048; q2 += 256) {
      int half = q2 >> 10, qq = q2 & 1023;
      int r = qq >> 4, c = qq & 15;
      const float* src = half ? (W + (size_t)(n0 + r) * K + kc + c * 4)
                              : (A + (size_t)(m0 + r) * K + kc + c * 4);
      float4 v = *(const float4*)src;
      if (half) sb[r][c] = v; else sa[r][c] = v;
    }
    __syncthreads();
#pragma unroll
    for (int c = 0; c < 16; ++c) {
      const int ks = (c + mt + nt) & 15;  // swizzle to break LDS bank conflicts
      float4 av[4], bv[4];
#pragma unroll
      for (int i = 0; i < 4; ++i) av[i] = sa[mt * 4 + i][ks];
#pragma unroll
      for (int j = 0; j < 4; ++j) bv[j] = sb[nt * 4 + j][ks];
#pragma unroll
      for (int i = 0; i < 4; ++i)
#pragma unroll
        for (int j = 0; j < 4; ++j) {
          acc[i][j] += av[i].x * bv[j].x;
          acc[i][j] += av[i].y * bv[j].y;
          acc[i][j] += av[i].z * bv[j].z;
          acc[i][j] += av[i].w * bv[j].w;
        }
    }
    __syncthreads();
  }
#pragma unroll
  for (int i = 0; i < 4; ++i)
#pragma unroll
    for (int j = 0; j < 4; ++j) {
      size_t o = (size_t)(m0 + mt * 4 + i) * Ntot + n0 + nt * 4 + j;
      float v = acc[i][j];
      if (RESID) v += Id[o];
      Out[o] = fmaxf(v, 0.0f);
    }
}

// ---------------------------------------------------------------- pad weights rows to 4-aligned cols
__global__ void k_pad_w(const float* __restrict__ src, float* __restrict__ dst,
                        int rows, int cin, int cp4) {
  int t = blockIdx.x * 256 + threadIdx.x;
  if (t >= rows * cp4) return;
  int r = t / cp4, c = t - r * cp4;
  dst[t] = (c < cin) ? src[(size_t)r * cin + c] : 0.0f;
}

// ---------------------------------------------------------------- out1 transpose (B*S,128) -> (B,128,S)
__global__ void k_out1_t(const float* __restrict__ in, float* __restrict__ out) {
  __shared__ float tile[32][33];
  const int b = blockIdx.z;
  const int s0 = blockIdx.x * 32, d0 = blockIdx.y * 32;
  const int tx = threadIdx.x, ty = threadIdx.y;
#pragma unroll
  for (int i = 0; i < 32; i += 8)
    tile[ty + i][tx] = in[(size_t)(b * SS + s0 + ty + i) * 128 + d0 + tx];
  __syncthreads();
#pragma unroll
  for (int i = 0; i < 32; i += 8)
    out[(size_t)(b * 128 + d0 + ty + i) * SS + s0 + tx] = tile[tx][ty + i];
}

// ----------------------------------------------------------------
extern "C" void kernel_launch(void* const* d_in, const int* in_sizes, int n_in,
                              void* d_out, int out_size, void* d_ws, size_t ws_size,
                              hipStream_t stream) {
  const float* pc    = (const float*)d_in[0];
  const float* pfea  = (const float*)d_in[1];
  const float* w_sa  = (const float*)d_in[2];
  const float* w_la1 = (const float*)d_in[3];
  const float* w1_1  = (const float*)d_in[4];
  const float* w2_1  = (const float*)d_in[5];
  const float* w_la2 = (const float*)d_in[6];
  const float* w1_2  = (const float*)d_in[7];
  const float* w2_2  = (const float*)d_in[8];
  float* out0 = (float*)d_out;
  float* out1 = out0 + (size_t)BB * 3 * SS;

  char* wsp = (char*)d_ws;
  size_t off = 0;
  auto alloc = [&](size_t bytes) -> void* {
    void* p = wsp + off;
    off = (off + bytes + 255) & ~(size_t)255;
    return p;
  };
  float* hbuf = (float*)alloc((size_t)BB * SS * HHV * 4);  // 16 MB; also aliased as feaT (disjoint in time)
  float* feaT = hbuf;                                      // 8 MB needed, used only before hbuf
  int*   fpsi = (int*)alloc((size_t)BB * SS * 4);
  float* ncoor = (float*)alloc((size_t)BB * SS * 3 * 4);
  int*   gi = (int*)alloc((size_t)BB * SS * GG * 4);
  float* fa = (float*)alloc((size_t)BB * SS * C2V * 4);
  float* fb = (float*)alloc((size_t)BB * SS * C2V * 4);
  float* wsap = (float*)alloc(128 * 68 * 4);
  float* wla1p = (float*)alloc(128 * 132 * 4);
  float* wla2p = (float*)alloc(128 * 132 * 4);

  k_pad_w<<<dim3((128 * 68 + 255) / 256), dim3(256), 0, stream>>>(w_sa, wsap, 128, 67, 68);
  k_pad_w<<<dim3((128 * 132 + 255) / 256), dim3(256), 0, stream>>>(w_la1, wla1p, 128, 131, 132);
  k_pad_w<<<dim3((128 * 132 + 255) / 256), dim3(256), 0, stream>>>(w_la2, wla2p, 128, 131, 132);

  k_transpose_fea<<<dim3(NN / 32, CC / 32, BB), dim3(32, 8), 0, stream>>>(pfea, feaT);
  k_fps<<<dim3(BB), dim3(1024), 0, stream>>>(pc, fpsi);
  k_gather<<<dim3((BB * SS + 255) / 256), dim3(256), 0, stream>>>(pc, fpsi, ncoor, out0);

  // stage 1: group among original N points, r=0.2
  k_knn<<<dim3(BB * SS / 2), dim3(256), 0, stream>>>(pc, ncoor, 0, NN, 0.04f, gi);
  k_group_mlp<64><<<dim3(BB * SS / 4), dim3(256), 0, stream>>>(feaT, gi, ncoor, pc, 0, NN, 0.2f, wsap, fa);

  // shared grouping for both inv-res blocks (same points, same radius 0.4)
  k_knn<<<dim3(BB * SS / 2), dim3(256), 0, stream>>>(ncoor, ncoor, 1, SS, 0.16f, gi);

  // inv-res block 1
  k_group_mlp<128><<<dim3(BB * SS / 4), dim3(256), 0, stream>>>(fa, gi, ncoor, ncoor, 1, SS, 0.4f, wla1p, fb);
  k_dense<false><<<dim3(128, 8), dim3(256), 0, stream>>>(fb, w1_1, nullptr, hbuf, 128, 512);
  k_dense<true><<<dim3(128, 2), dim3(256), 0, stream>>>(hbuf, w2_1, fa, fb, 512, 128);

  // inv-res block 2
  k_group_mlp<128><<<dim3(BB * SS / 4), dim3(256), 0, stream>>>(fb, gi, ncoor, ncoor, 1, SS, 0.4f, wla2p, fa);
  k_dense<false><<<dim3(128, 8), dim3(256), 0, stream>>>(fa, w1_2, nullptr, hbuf, 128, 512);
  k_dense<true><<<dim3(128, 2), dim3(256), 0, stream>>>(hbuf, w2_2, fb, fa, 512, 128);

  k_out1_t<<<dim3(SS / 32, 128 / 32, BB), dim3(32, 8), 0, stream>>>(fa, out1);
}

// Round 15
// 4598.192 us; speedup vs baseline: 1.0008x; 1.0008x over previous
//
#include <hip/hip_runtime.h>
#include <hip/hip_bf16.h>

#define BB 4
#define NN 8192
#define CC 64
#define SS 2048
#define GG 32
#define C2V 128
#define HHV 512

typedef unsigned long long u64;
typedef unsigned int u32;

// ---------------------------------------------------------------- transpose fea (B,C,N)->(B,N,C)
__global__ void k_transpose_fea(const float* __restrict__ in, float* __restrict__ out) {
  __shared__ float tile[32][33];
  const int b = blockIdx.z;
  const int n0 = blockIdx.x * 32, c0 = blockIdx.y * 32;
  const int tx = threadIdx.x, ty = threadIdx.y;
  const float* src = in + (size_t)b * CC * NN;
#pragma unroll
  for (int i = 0; i < 32; i += 8)
    tile[ty + i][tx] = src[(size_t)(c0 + ty + i) * NN + n0 + tx];
  __syncthreads();
  float* dst = out + (size_t)b * NN * CC;
#pragma unroll
  for (int i = 0; i < 32; i += 8)
    dst[(size_t)(n0 + ty + i) * CC + c0 + tx] = tile[tx][ty + i];
}

// ---------------------------------------------------------------- FPS (v8: AGPR-parked coords)
// FROZEN at r13: per-active-CU VALU ~98% -> at this structure's issue floor.
__global__ __launch_bounds__(1024, 4) void k_fps(const float* __restrict__ pc, int* __restrict__ fps_idx) {
#pragma clang fp contract(off)
  __shared__ float lx[NN], ly[NN], lz[NN];
  __shared__ int sIdx[SS];
  __shared__ u64 sK[2][16];
  const int b = blockIdx.x, tid = threadIdx.x;
  const int lane = tid & 63, wid = tid >> 6;
  const float* pb = pc + (size_t)b * 3 * NN;

  const float4* gx = (const float4*)pb;
  const float4* gy = (const float4*)(pb + NN);
  const float4* gz = (const float4*)(pb + 2 * NN);
  float4 vXa = gx[tid], vXb = gx[tid + 1024];
  float4 vYa = gy[tid], vYb = gy[tid + 1024];
  float4 vZa = gz[tid], vZb = gz[tid + 1024];
  {
    float4* sx = (float4*)lx; float4* sy = (float4*)ly; float4* sz = (float4*)lz;
    sx[tid] = vXa; sx[tid + 1024] = vXb;
    sy[tid] = vYa; sy[tid + 1024] = vYb;
    sz[tid] = vZa; sz[tid + 1024] = vZb;
  }
  float aXax, aXay, aXaz, aXaw, aXbx, aXby, aXbz, aXbw;
  float aYax, aYay, aYaz, aYaw, aYbx, aYby, aYbz, aYbw;
  float aZax, aZay, aZaz, aZaw, aZbx, aZby, aZbz, aZbw;
#define PARK(A, V) asm volatile("v_accvgpr_write_b32 %0, %1" : "=a"(A) : "v"(V));
  PARK(aXax, vXa.x) PARK(aXay, vXa.y) PARK(aXaz, vXa.z) PARK(aXaw, vXa.w)
  PARK(aXbx, vXb.x) PARK(aXby, vXb.y) PARK(aXbz, vXb.z) PARK(aXbw, vXb.w)
  PARK(aYax, vYa.x) PARK(aYay, vYa.y) PARK(aYaz, vYa.z) PARK(aYaw, vYa.w)
  PARK(aYbx, vYb.x) PARK(aYby, vYb.y) PARK(aYbz, vYb.z) PARK(aYbw, vYb.w)
  PARK(aZax, vZa.x) PARK(aZay, vZa.y) PARK(aZaz, vZa.z) PARK(aZaw, vZa.w)
  PARK(aZbx, vZb.x) PARK(aZby, vZb.y) PARK(aZbz, vZb.z) PARK(aZbw, vZb.w)
#undef PARK
  if (tid < 32) ((u64*)sK)[tid] = 0ull;
  if (tid == 0) sK[0][0] = ~0ull;   // step-0 winner: idx 0
  __syncthreads();

  const u32 ibase = (u32)(wid * 256 + lane * 4);
  float4 D0 = make_float4(1e20f, 1e20f, 1e20f, 1e20f);
  float4 D1 = D0;

#define DPPK64(K, CTL) { \
      u32 lo = (u32)(K), hi = (u32)((K) >> 32); \
      u32 lo2 = (u32)__builtin_amdgcn_update_dpp(0, (int)lo, CTL, 0xf, 0xf, false); \
      u32 hi2 = (u32)__builtin_amdgcn_update_dpp(0, (int)hi, CTL, 0xf, 0xf, false); \
      u64 k2 = ((u64)hi2 << 32) | (u64)lo2; if (k2 > (K)) (K) = k2; }
#define RMAXF(V, CTL) { \
      float t_ = __int_as_float(__builtin_amdgcn_update_dpp(0, __float_as_int(V), CTL, 0xf, 0xf, false)); \
      (V) = fmaxf((V), t_); }
#define RMINU(V, CTL) { \
      u32 t_ = (u32)__builtin_amdgcn_update_dpp(0, (int)(V), CTL, 0xf, 0xf, false); \
      (V) = min((V), t_); }
#define FETCH(V, A) asm volatile("v_accvgpr_read_b32 %0, %1" : "=v"(V) : "a"(A));

  for (int k = 0; k < SS; ++k) {
    const int p = k & 1, pn = p ^ 1;
    u64 kk = sK[p][lane & 15];
    float xax, xay, xaz, xaw, xbx, xby, xbz, xbw;
    float yax, yay, yaz, yaw, ybx, yby, ybz, ybw;
    float zax, zay, zaz, zaw, zbx, zby, zbz, zbw;
    FETCH(xax, aXax) FETCH(xay, aXay) FETCH(xaz, aXaz) FETCH(xaw, aXaw)
    FETCH(xbx, aXbx) FETCH(xby, aXby) FETCH(xbz, aXbz) FETCH(xbw, aXbw)
    FETCH(yax, aYax) FETCH(yay, aYay) FETCH(yaz, aYaz) FETCH(yaw, aYaw)
    FETCH(ybx, aYbx) FETCH(yby, aYby) FETCH(ybz, aYbz) FETCH(ybw, aYbw)
    FETCH(zax, aZax) FETCH(zay, aZay) FETCH(zaz, aZaz) FETCH(zaw, aZaw)
    FETCH(zbx, aZbx) FETCH(zby, aZby) FETCH(zbz, aZbz) FETCH(zbw, aZbw)
    DPPK64(kk, 0x121) DPPK64(kk, 0x122) DPPK64(kk, 0x124) DPPK64(kk, 0x128)
    const u32 idx = 0xFFFFFFFFu - (u32)kk;
    if (tid == 0) sIdx[k] = (int)idx;
    const float cx = lx[idx], cy = ly[idx], cz = lz[idx];

#define UPDC(XX, YY, ZZ, DD) { \
      float dx_ = (XX) - cx, dy_ = (YY) - cy, dz_ = (ZZ) - cz; \
      float t0_ = dx_ * dx_, t1_ = dy_ * dy_, t2_ = dz_ * dz_; \
      float s_ = (t0_ + t1_) + t2_; \
      (DD) = fminf((DD), s_); }
    UPDC(xax, yax, zax, D0.x) UPDC(xay, yay, zay, D0.y)
    UPDC(xaz, yaz, zaz, D0.z) UPDC(xaw, yaw, zaw, D0.w)
    UPDC(xbx, ybx, zbx, D1.x) UPDC(xby, yby, zby, D1.y)
    UPDC(xbz, ybz, zbz, D1.z) UPDC(xbw, ybw, zbw, D1.w)
#undef UPDC

    float m2 = fmaxf(fmaxf(fmaxf(D0.x, D0.y), fmaxf(D0.z, D0.w)),
                     fmaxf(fmaxf(D1.x, D1.y), fmaxf(D1.z, D1.w)));
    RMAXF(m2, 0x121) RMAXF(m2, 0x122) RMAXF(m2, 0x124) RMAXF(m2, 0x128)
    m2 = fmaxf(m2, __shfl_xor(m2, 16, 64));
    m2 = fmaxf(m2, __shfl_xor(m2, 32, 64));

    float s = sqrtf(m2);
    u32 sbits = __float_as_uint(s);
    float spred = __uint_as_float(sbits - 1u);
    double M = ((double)spred + (double)s) * 0.5;
    double L = M * M;
    if (sbits & 1u) L = __longlong_as_double(__double_as_longlong(L) + 1ll);
    float Lf = (float)L;
    if ((double)Lf < L) Lf = __uint_as_float(__float_as_uint(Lf) + 1u);

    u32 enc = 0xFFFFFFFFu;
    {
      int off = -1;
      if (D1.w >= Lf) off = 4096 + 3;
      if (D1.z >= Lf) off = 4096 + 2;
      if (D1.y >= Lf) off = 4096 + 1;
      if (D1.x >= Lf) off = 4096 + 0;
      if (D0.w >= Lf) off = 3;
      if (D0.z >= Lf) off = 2;
      if (D0.y >= Lf) off = 1;
      if (D0.x >= Lf) off = 0;
      if (off >= 0) enc = ibase + (u32)off;
    }
    RMINU(enc, 0x121) RMINU(enc, 0x122) RMINU(enc, 0x124) RMINU(enc, 0x128)
    enc = min(enc, (u32)__shfl_xor((int)enc, 16, 64));
    enc = min(enc, (u32)__shfl_xor((int)enc, 32, 64));

    if (lane == 0)
      sK[pn][wid] = (((u64)sbits) << 32) | (u64)(0xFFFFFFFFu - enc);
    __syncthreads();
  }
#undef DPPK64
#undef RMAXF
#undef RMINU
#undef FETCH
  fps_idx[b * SS + tid] = sIdx[tid];
  fps_idx[b * SS + 1024 + tid] = sIdx[1024 + tid];
}

// ---------------------------------------------------------------- gather new_coor + out0
__global__ void k_gather(const float* __restrict__ pc, const int* __restrict__ fps_idx,
                         float* __restrict__ ncoor, float* __restrict__ out0) {
  int t = blockIdx.x * 256 + threadIdx.x;
  if (t >= BB * SS) return;
  int b = t / SS, s = t % SS;
  int id = fps_idx[t];
  const float* base = pc + (size_t)b * 3 * NN;
  float x = base[id], y = base[NN + id], z = base[2 * NN + id];
  ncoor[(size_t)t * 3] = x; ncoor[(size_t)t * 3 + 1] = y; ncoor[(size_t)t * 3 + 2] = z;
  size_t o = (size_t)b * 3 * SS + s;
  out0[o] = x; out0[o + SS] = y; out0[o + 2 * SS] = z;
}

// ---------------------------------------------------------------- kNN, 2 queries per block
// Shares the candidate-point load stream between 2 queries (halves candp
// traffic). Distance math bit-identical to the verified r5+ chain: FMA-chain
// dot (np einsum under gcc contract=fast), contract-off materialized-squares
// norms, d = ((-2*dot)+qn)+pn. Selection logic per query unchanged.
__global__ __launch_bounds__(256) void k_knn(const float* __restrict__ candp,
                                             const float* __restrict__ newc,
                                             int mode, int ncand, float r2,
                                             int* __restrict__ gidx) {
  __shared__ float cd[2][2048];
  __shared__ int ci[2][2048];
  __shared__ int hist[2][64];
  __shared__ int cnt[2], oc[2], binT[2], mlow[2];
  const int q0 = blockIdx.x * 2, tid = threadIdx.x;
  const int b = q0 / SS;
  if (tid == 0) { cnt[0] = 0; cnt[1] = 0; oc[0] = 0; oc[1] = 0; }
  if (tid < 64) hist[0][tid] = 0;
  else if (tid < 128) hist[1][tid - 64] = 0;
  __syncthreads();
  const float qx0 = newc[(size_t)q0 * 3], qy0 = newc[(size_t)q0 * 3 + 1], qz0 = newc[(size_t)q0 * 3 + 2];
  const float qx1 = newc[(size_t)(q0 + 1) * 3], qy1 = newc[(size_t)(q0 + 1) * 3 + 1], qz1 = newc[(size_t)(q0 + 1) * 3 + 2];
  float qn0, qn1;
  {
#pragma clang fp contract(off)
    qn0 = (qx0 * qx0 + qy0 * qy0) + qz0 * qz0;
    qn1 = (qx1 * qx1 + qy1 * qy1) + qz1 * qz1;
  }
  const float sc = 64.0f / r2;
  const float* base = (mode == 0) ? candp + (size_t)b * 3 * NN : candp + (size_t)b * SS * 3;
  for (int i = tid; i < ncand; i += 256) {
    float x, y, z;
    if (mode == 0) { x = base[i]; y = base[NN + i]; z = base[2 * NN + i]; }
    else { x = base[3 * i]; y = base[3 * i + 1]; z = base[3 * i + 2]; }
    {
      float dot = fmaf(qz0, z, fmaf(qy0, y, qx0 * x));
      float d;
      {
#pragma clang fp contract(off)
        float pn = (x * x + y * y) + z * z;
        d = ((-2.0f * dot) + qn0) + pn;
      }
      if (d <= r2) {
        int pp = atomicAdd(&cnt[0], 1);
        if (pp < 2048) { cd[0][pp] = d; ci[0][pp] = i; }
        float db = (d > 0.0f) ? d : 0.0f;
        atomicAdd(&hist[0][min(63, (int)(db * sc))], 1);
      }
    }
    {
      float dot = fmaf(qz1, z, fmaf(qy1, y, qx1 * x));
      float d;
      {
#pragma clang fp contract(off)
        float pn = (x * x + y * y) + z * z;
        d = ((-2.0f * dot) + qn1) + pn;
      }
      if (d <= r2) {
        int pp = atomicAdd(&cnt[1], 1);
        if (pp < 2048) { cd[1][pp] = d; ci[1][pp] = i; }
        float db = (d > 0.0f) ? d : 0.0f;
        atomicAdd(&hist[1][min(63, (int)(db * sc))], 1);
      }
    }
  }
  __syncthreads();
  if (tid == 0) {
#pragma unroll
    for (int jq = 0; jq < 2; ++jq) {
      const int M = min(cnt[jq], 2048);
      if (M > 32) {
        int c = 0, t = 0;
        for (t = 0; t < 64; ++t) { if (c + hist[jq][t] >= 32) break; c += hist[jq][t]; }
        binT[jq] = t; mlow[jq] = c;
      } else binT[jq] = -1;
    }
  }
  __syncthreads();
  for (int jq = 0; jq < 2; ++jq) {
    const int M = min(cnt[jq], 2048);
    int* out = gidx + (size_t)(q0 + jq) * 32;
    if (binT[jq] < 0) {
      for (int j = tid; j < M; j += 256) out[atomicAdd(&oc[jq], 1)] = ci[jq][j];
      __syncthreads();
      if (tid == 0 && M < 32) {
        float bd = 1e30f; int bx = 0x7FFFFFFF;
        for (int j = 0; j < M; ++j)
          if (cd[jq][j] < bd || (cd[jq][j] == bd && ci[jq][j] < bx)) { bd = cd[jq][j]; bx = ci[jq][j]; }
        for (int j = M; j < 32; ++j) out[j] = bx;
      }
    } else {
      const int bt = binT[jq], m = mlow[jq];
      for (int j = tid; j < M; j += 256) {
        float dbj = (cd[jq][j] > 0.0f) ? cd[jq][j] : 0.0f;
        int bin = min(63, (int)(dbj * sc));
        if (bin < bt) out[atomicAdd(&oc[jq], 1)] = ci[jq][j];
        else if (bin == bt) {
          int r = 0; const float dj = cd[jq][j]; const int ij = ci[jq][j];
          for (int kk = 0; kk < M; ++kk) {
            float dbk = (cd[jq][kk] > 0.0f) ? cd[jq][kk] : 0.0f;
            if (min(63, (int)(dbk * sc)) == bt &&
                (cd[jq][kk] < dj || (cd[jq][kk] == dj && ci[jq][kk] < ij))) ++r;
          }
          if (m + r < 32) out[m + r] = ci[jq][j];
        }
      }
    }
    __syncthreads();
  }
}

// ---------------------------------------------------------------- grouped MLP + max  (out 128 ch)
// e-chunked: neighbors processed in 2 chunks of 16 -> g4 LDS halves
// (FDIM=128: 33.8->16.9 KB) -> ~2x blocks/CU to hide the random-row gather
// latency. Max over chunks is exact; per-(row,d,e) dot-product accumulation
// order unchanged. Weight reads double but are L1/L2-hot broadcast.
template <int FDIM>
__global__ __launch_bounds__(256) void k_group_mlp(
    const float* __restrict__ fea, const int* __restrict__ gidx,
    const float* __restrict__ newc, const float* __restrict__ candp,
    int mode, int ncand, float radius,
    const float* __restrict__ wp, float* __restrict__ outf) {
  constexpr int CP4 = FDIM + 4;     // padded cols (67->68, 131->132)
  constexpr int NC4 = CP4 / 4;
  __shared__ float4 g4[2][16][NC4];
  __shared__ int sidx[2][32];
  __shared__ float sq[2][3];
  __shared__ float pf[2][4][128];
  const int tid = threadIdx.x;
  const int rs = tid >> 7, tl = tid & 127;
  const int dt = tl & 31, et = tl >> 5;   // 32 d-threads x 4 e-threads
  const int d0 = dt * 4, e0 = et * 4;     // 4 d, 4 e each (16 e per chunk)
  const int row0 = blockIdx.x * 4;
  for (int rp = 0; rp < 4; rp += 2) {
    const int row = row0 + rp + rs;
    if (tl < 32) sidx[rs][tl] = gidx[(size_t)row * 32 + tl];
    if (tl < 3) sq[rs][tl] = newc[(size_t)row * 3 + tl];
    __syncthreads();
    const int bb2 = row / SS;
    const float* fb = fea + (size_t)bb2 * ncand * FDIM;
    const float* cb = (mode == 0) ? candp + (size_t)bb2 * 3 * NN
                                  : candp + (size_t)bb2 * SS * 3;
    float* gf = (float*)&g4[rs][0][0];
    const float4* w4 = (const float4*)wp;
    float rmax[4];
#pragma unroll
    for (int i = 0; i < 4; ++i) rmax[i] = -1e30f;
    for (int ec = 0; ec < 2; ++ec) {
      // stage chunk ec (16 neighbors)
      for (int qq = tl; qq < 16 * CP4; qq += 128) {
        int e = qq / CP4, c = qq - e * CP4;
        int id = sidx[rs][ec * 16 + e];
        float v;
        if (c < FDIM) v = fb[(size_t)id * FDIM + c];
        else if (c < FDIM + 3) {
          int comp = c - FDIM;
          float pcv = (mode == 0) ? cb[(size_t)comp * NN + id] : cb[(size_t)id * 3 + comp];
          v = (pcv - sq[rs][comp]) / radius;
        } else v = 0.0f;
        gf[qq] = v;
      }
      __syncthreads();
      float acc[4][4];
#pragma unroll
      for (int i = 0; i < 4; ++i)
#pragma unroll
        for (int j = 0; j < 4; ++j) acc[i][j] = 0.0f;
      for (int c4 = 0; c4 < NC4; ++c4) {
        float4 wv[4], gv[4];
#pragma unroll
        for (int i = 0; i < 4; ++i) wv[i] = w4[(size_t)(d0 + i) * NC4 + c4];
#pragma unroll
        for (int j = 0; j < 4; ++j) gv[j] = g4[rs][e0 + j][c4];
#pragma unroll
        for (int i = 0; i < 4; ++i)
#pragma unroll
          for (int j = 0; j < 4; ++j) {
            acc[i][j] += wv[i].x * gv[j].x;
            acc[i][j] += wv[i].y * gv[j].y;
            acc[i][j] += wv[i].z * gv[j].z;
            acc[i][j] += wv[i].w * gv[j].w;
          }
      }
#pragma unroll
      for (int i = 0; i < 4; ++i)
#pragma unroll
        for (int j = 0; j < 4; ++j) rmax[i] = fmaxf(rmax[i], acc[i][j]);
      __syncthreads();  // g4 reused next chunk
    }
#pragma unroll
    for (int i = 0; i < 4; ++i) pf[rs][et][d0 + i] = rmax[i];
    __syncthreads();
    {
      const int d = tid & 127, r2s = tid >> 7;
      const int rowW = row0 + rp + r2s;
      float m = fmaxf(fmaxf(pf[r2s][0][d], pf[r2s][1][d]),
                      fmaxf(pf[r2s][2][d], pf[r2s][3][d]));
      outf[(size_t)rowW * 128 + d] = fmaxf(m, 0.0f);
    }
    __syncthreads();
  }
}

// ---------------------------------------------------------------- dense GEMM: Out = relu(A(M,K) * W(N,K)^T [+ Id])
template <bool RESID>
__global__ __launch_bounds__(256) void k_dense(
    const float* __restrict__ A, const float* __restrict__ W,
    const float* __restrict__ Id, float* __restrict__ Out,
    int K, int Ntot) {
  __shared__ float4 sa[64][17], sb[64][17];
  const int m0 = blockIdx.x * 64, n0 = blockIdx.y * 64;
  const int tid = threadIdx.x;
  const int mt = tid & 15, nt = tid >> 4;
  float acc[4][4];
#pragma unroll
  for (int i = 0; i < 4; ++i)
#pragma unroll
    for (int j = 0; j < 4; ++j) acc[i][j] = 0.0f;
  for (int kc = 0; kc < K; kc += 64) {
    for (int q2 = tid; q2 < 2048; q2 += 256) {
      int half = q2 >> 10, qq = q2 & 1023;
      int r = qq >> 4, c = qq & 15;
      const float* src = half ? (W + (size_t)(n0 + r) * K + kc + c * 4)
                              : (A + (size_t)(m0 + r) * K + kc + c * 4);
      float4 v = *(const float4*)src;
      if (half) sb[r][c] = v; else sa[r][c] = v;
    }
    __syncthreads();
#pragma unroll
    for (int c = 0; c < 16; ++c) {
      const int ks = (c + mt + nt) & 15;  // swizzle to break LDS bank conflicts
      float4 av[4], bv[4];
#pragma unroll
      for (int i = 0; i < 4; ++i) av[i] = sa[mt * 4 + i][ks];
#pragma unroll
      for (int j = 0; j < 4; ++j) bv[j] = sb[nt * 4 + j][ks];
#pragma unroll
      for (int i = 0; i < 4; ++i)
#pragma unroll
        for (int j = 0; j < 4; ++j) {
          acc[i][j] += av[i].x * bv[j].x;
          acc[i][j] += av[i].y * bv[j].y;
          acc[i][j] += av[i].z * bv[j].z;
          acc[i][j] += av[i].w * bv[j].w;
        }
    }
    __syncthreads();
  }
#pragma unroll
  for (int i = 0; i < 4; ++i)
#pragma unroll
    for (int j = 0; j < 4; ++j) {
      size_t o = (size_t)(m0 + mt * 4 + i) * Ntot + n0 + nt * 4 + j;
      float v = acc[i][j];
      if (RESID) v += Id[o];
      Out[o] = fmaxf(v, 0.0f);
    }
}

// ---------------------------------------------------------------- pad weights rows to 4-aligned cols
__global__ void k_pad_w(const float* __restrict__ src, float* __restrict__ dst,
                        int rows, int cin, int cp4) {
  int t = blockIdx.x * 256 + threadIdx.x;
  if (t >= rows * cp4) return;
  int r = t / cp4, c = t - r * cp4;
  dst[t] = (c < cin) ? src[(size_t)r * cin + c] : 0.0f;
}

// ---------------------------------------------------------------- out1 transpose (B*S,128) -> (B,128,S)
__global__ void k_out1_t(const float* __restrict__ in, float* __restrict__ out) {
  __shared__ float tile[32][33];
  const int b = blockIdx.z;
  const int s0 = blockIdx.x * 32, d0 = blockIdx.y * 32;
  const int tx = threadIdx.x, ty = threadIdx.y;
#pragma unroll
  for (int i = 0; i < 32; i += 8)
    tile[ty + i][tx] = in[(size_t)(b * SS + s0 + ty + i) * 128 + d0 + tx];
  __syncthreads();
#pragma unroll
  for (int i = 0; i < 32; i += 8)
    out[(size_t)(b * 128 + d0 + ty + i) * SS + s0 + tx] = tile[tx][ty + i];
}

// ----------------------------------------------------------------
extern "C" void kernel_launch(void* const* d_in, const int* in_sizes, int n_in,
                              void* d_out, int out_size, void* d_ws, size_t ws_size,
                              hipStream_t stream) {
  const float* pc    = (const float*)d_in[0];
  const float* pfea  = (const float*)d_in[1];
  const float* w_sa  = (const float*)d_in[2];
  const float* w_la1 = (const float*)d_in[3];
  const float* w1_1  = (const float*)d_in[4];
  const float* w2_1  = (const float*)d_in[5];
  const float* w_la2 = (const float*)d_in[6];
  const float* w1_2  = (const float*)d_in[7];
  const float* w2_2  = (const float*)d_in[8];
  float* out0 = (float*)d_out;
  float* out1 = out0 + (size_t)BB * 3 * SS;

  char* wsp = (char*)d_ws;
  size_t off = 0;
  auto alloc = [&](size_t bytes) -> void* {
    void* p = wsp + off;
    off = (off + bytes + 255) & ~(size_t)255;
    return p;
  };
  float* hbuf = (float*)alloc((size_t)BB * SS * HHV * 4);  // 16 MB; also aliased as feaT (disjoint in time)
  float* feaT = hbuf;                                      // 8 MB needed, used only before hbuf
  int*   fpsi = (int*)alloc((size_t)BB * SS * 4);
  float* ncoor = (float*)alloc((size_t)BB * SS * 3 * 4);
  int*   gi = (int*)alloc((size_t)BB * SS * GG * 4);
  float* fa = (float*)alloc((size_t)BB * SS * C2V * 4);
  float* fb = (float*)alloc((size_t)BB * SS * C2V * 4);
  float* wsap = (float*)alloc(128 * 68 * 4);
  float* wla1p = (float*)alloc(128 * 132 * 4);
  float* wla2p = (float*)alloc(128 * 132 * 4);

  k_pad_w<<<dim3((128 * 68 + 255) / 256), dim3(256), 0, stream>>>(w_sa, wsap, 128, 67, 68);
  k_pad_w<<<dim3((128 * 132 + 255) / 256), dim3(256), 0, stream>>>(w_la1, wla1p, 128, 131, 132);
  k_pad_w<<<dim3((128 * 132 + 255) / 256), dim3(256), 0, stream>>>(w_la2, wla2p, 128, 131, 132);

  k_transpose_fea<<<dim3(NN / 32, CC / 32, BB), dim3(32, 8), 0, stream>>>(pfea, feaT);
  k_fps<<<dim3(BB), dim3(1024), 0, stream>>>(pc, fpsi);
  k_gather<<<dim3((BB * SS + 255) / 256), dim3(256), 0, stream>>>(pc, fpsi, ncoor, out0);

  // stage 1: group among original N points, r=0.2
  k_knn<<<dim3(BB * SS / 2), dim3(256), 0, stream>>>(pc, ncoor, 0, NN, 0.04f, gi);
  k_group_mlp<64><<<dim3(BB * SS / 4), dim3(256), 0, stream>>>(feaT, gi, ncoor, pc, 0, NN, 0.2f, wsap, fa);

  // shared grouping for both inv-res blocks (same points, same radius 0.4)
  k_knn<<<dim3(BB * SS / 2), dim3(256), 0, stream>>>(ncoor, ncoor, 1, SS, 0.16f, gi);

  // inv-res block 1
  k_group_mlp<128><<<dim3(BB * SS / 4), dim3(256), 0, stream>>>(fa, gi, ncoor, ncoor, 1, SS, 0.4f, wla1p, fb);
  k_dense<false><<<dim3(128, 8), dim3(256), 0, stream>>>(fb, w1_1, nullptr, hbuf, 128, 512);
  k_dense<true><<<dim3(128, 2), dim3(256), 0, stream>>>(hbuf, w2_1, fa, fb, 512, 128);

  // inv-res block 2
  k_group_mlp<128><<<dim3(BB * SS / 4), dim3(256), 0, stream>>>(fb, gi, ncoor, ncoor, 1, SS, 0.4f, wla2p, fa);
  k_dense<false><<<dim3(128, 8), dim3(256), 0, stream>>>(fa, w1_2, nullptr, hbuf, 128, 512);
  k_dense<true><<<dim3(128, 2), dim3(256), 0, stream>>>(hbuf, w2_2, fb, fa, 512, 128);

  k_out1_t<<<dim3(SS / 32, 128 / 32, BB), dim3(32, 8), 0, stream>>>(fa, out1);
}

// Round 16
// 3716.144 us; speedup vs baseline: 1.2383x; 1.2374x over previous
//
#include <hip/hip_runtime.h>
#include <hip/hip_bf16.h>

#define BB 4
#define NN 8192
#define CC 64
#define SS 2048
#define GG 32
#define C2V 128
#define HHV 512

typedef unsigned long long u64;
typedef unsigned int u32;

// ---------------------------------------------------------------- transpose fea (B,C,N)->(B,N,C)
__global__ void k_transpose_fea(const float* __restrict__ in, float* __restrict__ out) {
  __shared__ float tile[32][33];
  const int b = blockIdx.z;
  const int n0 = blockIdx.x * 32, c0 = blockIdx.y * 32;
  const int tx = threadIdx.x, ty = threadIdx.y;
  const float* src = in + (size_t)b * CC * NN;
#pragma unroll
  for (int i = 0; i < 32; i += 8)
    tile[ty + i][tx] = src[(size_t)(c0 + ty + i) * NN + n0 + tx];
  __syncthreads();
  float* dst = out + (size_t)b * NN * CC;
#pragma unroll
  for (int i = 0; i < 32; i += 8)
    dst[(size_t)(n0 + ty + i) * CC + c0 + tx] = tile[tx][ty + i];
}

// ---------------------------------------------------------------- FPS (v9: 512 thr + AGPR)
// r7's 512-thread geometry (measured-best 2755 us even WITH scratch arrays)
// + r13's AGPR parking (48 coord floats/lane, removes r7's scratch handicap)
// + r11's LDS winner-broadcast. 8 waves = 2/SIMD: halves the per-step fixed
// reduce issue cost vs 16 waves and shortens the lockstep drain.
// Numerics = verified r11-r15 chain, bit-identical: contract-off materialized
// squares, wave-uniform correctly-rounded sqrt, exact f64 preimage floor of
// s's rounding interval, first-index via min-enc butterflies (lane owns 16
// CONSECUTIVE points tid*16..tid*16+15 -> min enc == smallest global index).
__global__ __launch_bounds__(512, 2) void k_fps(const float* __restrict__ pc, int* __restrict__ fps_idx) {
#pragma clang fp contract(off)
  __shared__ float lx[NN], ly[NN], lz[NN];
  __shared__ int sIdx[SS];
  __shared__ u64 sK[2][8];
  const int b = blockIdx.x, tid = threadIdx.x;
  const int lane = tid & 63, wid = tid >> 6;
  const float* pb = pc + (size_t)b * 3 * NN;

  const float4* gx = (const float4*)pb;
  const float4* gy = (const float4*)(pb + NN);
  const float4* gz = (const float4*)(pb + 2 * NN);
  float4 vX0 = gx[tid * 4 + 0], vX1 = gx[tid * 4 + 1], vX2 = gx[tid * 4 + 2], vX3 = gx[tid * 4 + 3];
  float4 vY0 = gy[tid * 4 + 0], vY1 = gy[tid * 4 + 1], vY2 = gy[tid * 4 + 2], vY3 = gy[tid * 4 + 3];
  float4 vZ0 = gz[tid * 4 + 0], vZ1 = gz[tid * 4 + 1], vZ2 = gz[tid * 4 + 2], vZ3 = gz[tid * 4 + 3];
  {
    float4* sx = (float4*)lx; float4* sy = (float4*)ly; float4* sz = (float4*)lz;
    sx[tid * 4 + 0] = vX0; sx[tid * 4 + 1] = vX1; sx[tid * 4 + 2] = vX2; sx[tid * 4 + 3] = vX3;
    sy[tid * 4 + 0] = vY0; sy[tid * 4 + 1] = vY1; sy[tid * 4 + 2] = vY2; sy[tid * 4 + 3] = vY3;
    sz[tid * 4 + 0] = vZ0; sz[tid * 4 + 1] = vZ1; sz[tid * 4 + 2] = vZ2; sz[tid * 4 + 3] = vZ3;
  }
  // park all 48 coord floats in AGPRs (cannot be rematerialized/spilled)
  float aX0x, aX0y, aX0z, aX0w, aX1x, aX1y, aX1z, aX1w;
  float aX2x, aX2y, aX2z, aX2w, aX3x, aX3y, aX3z, aX3w;
  float aY0x, aY0y, aY0z, aY0w, aY1x, aY1y, aY1z, aY1w;
  float aY2x, aY2y, aY2z, aY2w, aY3x, aY3y, aY3z, aY3w;
  float aZ0x, aZ0y, aZ0z, aZ0w, aZ1x, aZ1y, aZ1z, aZ1w;
  float aZ2x, aZ2y, aZ2z, aZ2w, aZ3x, aZ3y, aZ3z, aZ3w;
#define PARK(A, V) asm volatile("v_accvgpr_write_b32 %0, %1" : "=a"(A) : "v"(V));
  PARK(aX0x, vX0.x) PARK(aX0y, vX0.y) PARK(aX0z, vX0.z) PARK(aX0w, vX0.w)
  PARK(aX1x, vX1.x) PARK(aX1y, vX1.y) PARK(aX1z, vX1.z) PARK(aX1w, vX1.w)
  PARK(aX2x, vX2.x) PARK(aX2y, vX2.y) PARK(aX2z, vX2.z) PARK(aX2w, vX2.w)
  PARK(aX3x, vX3.x) PARK(aX3y, vX3.y) PARK(aX3z, vX3.z) PARK(aX3w, vX3.w)
  PARK(aY0x, vY0.x) PARK(aY0y, vY0.y) PARK(aY0z, vY0.z) PARK(aY0w, vY0.w)
  PARK(aY1x, vY1.x) PARK(aY1y, vY1.y) PARK(aY1z, vY1.z) PARK(aY1w, vY1.w)
  PARK(aY2x, vY2.x) PARK(aY2y, vY2.y) PARK(aY2z, vY2.z) PARK(aY2w, vY2.w)
  PARK(aY3x, vY3.x) PARK(aY3y, vY3.y) PARK(aY3z, vY3.z) PARK(aY3w, vY3.w)
  PARK(aZ0x, vZ0.x) PARK(aZ0y, vZ0.y) PARK(aZ0z, vZ0.z) PARK(aZ0w, vZ0.w)
  PARK(aZ1x, vZ1.x) PARK(aZ1y, vZ1.y) PARK(aZ1z, vZ1.z) PARK(aZ1w, vZ1.w)
  PARK(aZ2x, vZ2.x) PARK(aZ2y, vZ2.y) PARK(aZ2z, vZ2.z) PARK(aZ2w, vZ2.w)
  PARK(aZ3x, vZ3.x) PARK(aZ3y, vZ3.y) PARK(aZ3z, vZ3.z) PARK(aZ3w, vZ3.w)
#undef PARK
  if (lane == 0) sK[0][wid] = 0ull;
  if (tid == 0) sK[0][0] = ~0ull;   // step-0 winner: idx 0
  __syncthreads();

  const u32 ibase = (u32)(tid * 16);   // lane owns 16 consecutive points
  float4 D0 = make_float4(1e20f, 1e20f, 1e20f, 1e20f);
  float4 D1 = D0, D2q = D0, D3 = D0;

#define DPPK64(K, CTL) { \
      u32 lo = (u32)(K), hi = (u32)((K) >> 32); \
      u32 lo2 = (u32)__builtin_amdgcn_update_dpp(0, (int)lo, CTL, 0xf, 0xf, false); \
      u32 hi2 = (u32)__builtin_amdgcn_update_dpp(0, (int)hi, CTL, 0xf, 0xf, false); \
      u64 k2 = ((u64)hi2 << 32) | (u64)lo2; if (k2 > (K)) (K) = k2; }
#define RMAXF(V, CTL) { \
      float t_ = __int_as_float(__builtin_amdgcn_update_dpp(0, __float_as_int(V), CTL, 0xf, 0xf, false)); \
      (V) = fmaxf((V), t_); }
#define RMINU(V, CTL) { \
      u32 t_ = (u32)__builtin_amdgcn_update_dpp(0, (int)(V), CTL, 0xf, 0xf, false); \
      (V) = min((V), t_); }
#define FETCH(V, A) asm volatile("v_accvgpr_read_b32 %0, %1" : "=v"(V) : "a"(A));

  for (int k = 0; k < SS; ++k) {
    const int p = k & 1, pn = p ^ 1;
    // key read (slots repeat every 8 lanes); coords fetched from AGPRs underneath
    u64 kk = sK[p][lane & 7];
    float x0x, x0y, x0z, x0w, x1x, x1y, x1z, x1w;
    float x2x, x2y, x2z, x2w, x3x, x3y, x3z, x3w;
    float y0x, y0y, y0z, y0w, y1x, y1y, y1z, y1w;
    float y2x, y2y, y2z, y2w, y3x, y3y, y3z, y3w;
    float z0x, z0y, z0z, z0w, z1x, z1y, z1z, z1w;
    float z2x, z2y, z2z, z2w, z3x, z3y, z3z, z3w;
    FETCH(x0x, aX0x) FETCH(x0y, aX0y) FETCH(x0z, aX0z) FETCH(x0w, aX0w)
    FETCH(x1x, aX1x) FETCH(x1y, aX1y) FETCH(x1z, aX1z) FETCH(x1w, aX1w)
    FETCH(x2x, aX2x) FETCH(x2y, aX2y) FETCH(x2z, aX2z) FETCH(x2w, aX2w)
    FETCH(x3x, aX3x) FETCH(x3y, aX3y) FETCH(x3z, aX3z) FETCH(x3w, aX3w)
    FETCH(y0x, aY0x) FETCH(y0y, aY0y) FETCH(y0z, aY0z) FETCH(y0w, aY0w)
    FETCH(y1x, aY1x) FETCH(y1y, aY1y) FETCH(y1z, aY1z) FETCH(y1w, aY1w)
    FETCH(y2x, aY2x) FETCH(y2y, aY2y) FETCH(y2z, aY2z) FETCH(y2w, aY2w)
    FETCH(y3x, aY3x) FETCH(y3y, aY3y) FETCH(y3z, aY3z) FETCH(y3w, aY3w)
    FETCH(z0x, aZ0x) FETCH(z0y, aZ0y) FETCH(z0z, aZ0z) FETCH(z0w, aZ0w)
    FETCH(z1x, aZ1x) FETCH(z1y, aZ1y) FETCH(z1z, aZ1z) FETCH(z1w, aZ1w)
    FETCH(z2x, aZ2x) FETCH(z2y, aZ2y) FETCH(z2z, aZ2z) FETCH(z2w, aZ2w)
    FETCH(z3x, aZ3x) FETCH(z3y, aZ3y) FETCH(z3z, aZ3z) FETCH(z3w, aZ3w)
    // cross-wave winner: 8 slots -> 3 DPP row_ror steps
    DPPK64(kk, 0x121) DPPK64(kk, 0x122) DPPK64(kk, 0x124)
    const u32 idx = 0xFFFFFFFFu - (u32)kk;
    if (tid == 0) sIdx[k] = (int)idx;
    const float cx = lx[idx], cy = ly[idx], cz = lz[idx];  // same-addr broadcast

#define UPDC(XX, YY, ZZ, DD) { \
      float dx_ = (XX) - cx, dy_ = (YY) - cy, dz_ = (ZZ) - cz; \
      float t0_ = dx_ * dx_, t1_ = dy_ * dy_, t2_ = dz_ * dz_; \
      float s_ = (t0_ + t1_) + t2_; \
      (DD) = fminf((DD), s_); }
    UPDC(x0x, y0x, z0x, D0.x) UPDC(x0y, y0y, z0y, D0.y)
    UPDC(x0z, y0z, z0z, D0.z) UPDC(x0w, y0w, z0w, D0.w)
    UPDC(x1x, y1x, z1x, D1.x) UPDC(x1y, y1y, z1y, D1.y)
    UPDC(x1z, y1z, z1z, D1.z) UPDC(x1w, y1w, z1w, D1.w)
    UPDC(x2x, y2x, z2x, D2q.x) UPDC(x2y, y2y, z2y, D2q.y)
    UPDC(x2z, y2z, z2z, D2q.z) UPDC(x2w, y2w, z2w, D2q.w)
    UPDC(x3x, y3x, z3x, D3.x) UPDC(x3y, y3y, z3y, D3.y)
    UPDC(x3z, y3z, z3z, D3.z) UPDC(x3w, y3w, z3w, D3.w)
#undef UPDC

    float m2 = fmaxf(
        fmaxf(fmaxf(fmaxf(D0.x, D0.y), fmaxf(D0.z, D0.w)),
              fmaxf(fmaxf(D1.x, D1.y), fmaxf(D1.z, D1.w))),
        fmaxf(fmaxf(fmaxf(D2q.x, D2q.y), fmaxf(D2q.z, D2q.w)),
              fmaxf(fmaxf(D3.x, D3.y), fmaxf(D3.z, D3.w))));
    RMAXF(m2, 0x121) RMAXF(m2, 0x122) RMAXF(m2, 0x124) RMAXF(m2, 0x128)
    m2 = fmaxf(m2, __shfl_xor(m2, 16, 64));
    m2 = fmaxf(m2, __shfl_xor(m2, 32, 64));   // wave max (uniform)

    // wave-uniform: s = fl(sqrt(m2)), exact f64 preimage floor Lf
    float s = sqrtf(m2);
    u32 sbits = __float_as_uint(s);
    float spred = __uint_as_float(sbits - 1u);
    double M = ((double)spred + (double)s) * 0.5;
    double L = M * M;
    if (sbits & 1u) L = __longlong_as_double(__double_as_longlong(L) + 1ll);
    float Lf = (float)L;
    if ((double)Lf < L) Lf = __uint_as_float(__float_as_uint(Lf) + 1u);

    // first (smallest global index) candidate per lane: descending cascade
    u32 enc = 0xFFFFFFFFu;
    {
      int off = -1;
      if (D3.w >= Lf) off = 15;
      if (D3.z >= Lf) off = 14;
      if (D3.y >= Lf) off = 13;
      if (D3.x >= Lf) off = 12;
      if (D2q.w >= Lf) off = 11;
      if (D2q.z >= Lf) off = 10;
      if (D2q.y >= Lf) off = 9;
      if (D2q.x >= Lf) off = 8;
      if (D1.w >= Lf) off = 7;
      if (D1.z >= Lf) off = 6;
      if (D1.y >= Lf) off = 5;
      if (D1.x >= Lf) off = 4;
      if (D0.w >= Lf) off = 3;
      if (D0.z >= Lf) off = 2;
      if (D0.y >= Lf) off = 1;
      if (D0.x >= Lf) off = 0;
      if (off >= 0) enc = ibase + (u32)off;
    }
    RMINU(enc, 0x121) RMINU(enc, 0x122) RMINU(enc, 0x124) RMINU(enc, 0x128)
    enc = min(enc, (u32)__shfl_xor((int)enc, 16, 64));
    enc = min(enc, (u32)__shfl_xor((int)enc, 32, 64));

    if (lane == 0)
      sK[pn][wid] = (((u64)sbits) << 32) | (u64)(0xFFFFFFFFu - enc);
    __syncthreads();  // single barrier per step
  }
#undef DPPK64
#undef RMAXF
#undef RMINU
#undef FETCH
  // bulk writeout (coalesced)
#pragma unroll
  for (int q = 0; q < 4; ++q)
    fps_idx[b * SS + q * 512 + tid] = sIdx[q * 512 + tid];
}

// ---------------------------------------------------------------- gather new_coor + out0
__global__ void k_gather(const float* __restrict__ pc, const int* __restrict__ fps_idx,
                         float* __restrict__ ncoor, float* __restrict__ out0) {
  int t = blockIdx.x * 256 + threadIdx.x;
  if (t >= BB * SS) return;
  int b = t / SS, s = t % SS;
  int id = fps_idx[t];
  const float* base = pc + (size_t)b * 3 * NN;
  float x = base[id], y = base[NN + id], z = base[2 * NN + id];
  ncoor[(size_t)t * 3] = x; ncoor[(size_t)t * 3 + 1] = y; ncoor[(size_t)t * 3 + 2] = z;
  size_t o = (size_t)b * 3 * SS + s;
  out0[o] = x; out0[o + SS] = y; out0[o + 2 * SS] = z;
}

// ---------------------------------------------------------------- kNN (k=32 within radius, fill with argmin)
// REVERTED to r13 (1 query/block): the 2q variant cut occupancy 9->4 blocks/CU
// and serialized two selection phases -- measured regression.
__global__ __launch_bounds__(256) void k_knn(const float* __restrict__ candp,
                                             const float* __restrict__ newc,
                                             int mode, int ncand, float r2,
                                             int* __restrict__ gidx) {
  __shared__ float cd[2048];
  __shared__ int ci[2048];
  __shared__ int hist[64];
  __shared__ int cnt, oc, binT, mlow;
  const int q = blockIdx.x, tid = threadIdx.x;
  const int b = q / SS;
  if (tid == 0) { cnt = 0; oc = 0; }
  if (tid < 64) hist[tid] = 0;
  __syncthreads();
  const float qx = newc[(size_t)q * 3], qy = newc[(size_t)q * 3 + 1], qz = newc[(size_t)q * 3 + 2];
  float qn;
  {
#pragma clang fp contract(off)
    qn = (qx * qx + qy * qy) + qz * qz;
  }
  const float sc = 64.0f / r2;
  const float* base = (mode == 0) ? candp + (size_t)b * 3 * NN : candp + (size_t)b * SS * 3;
  for (int i = tid; i < ncand; i += 256) {
    float x, y, z;
    if (mode == 0) { x = base[i]; y = base[NN + i]; z = base[2 * NN + i]; }
    else { x = base[3 * i]; y = base[3 * i + 1]; z = base[3 * i + 2]; }
    float dot = fmaf(qz, z, fmaf(qy, y, qx * x));
    float d;
    {
#pragma clang fp contract(off)
      float pn = (x * x + y * y) + z * z;
      d = ((-2.0f * dot) + qn) + pn;
    }
    if (d <= r2) {
      int pp = atomicAdd(&cnt, 1);
      if (pp < 2048) { cd[pp] = d; ci[pp] = i; }
      float db = (d > 0.0f) ? d : 0.0f;
      atomicAdd(&hist[min(63, (int)(db * sc))], 1);
    }
  }
  __syncthreads();
  const int M = min(cnt, 2048);
  if (tid == 0) {
    if (M > 32) {
      int c = 0, t = 0;
      for (t = 0; t < 64; ++t) { if (c + hist[t] >= 32) break; c += hist[t]; }
      binT = t; mlow = c;
    } else binT = -1;
  }
  __syncthreads();
  int* out = gidx + (size_t)q * 32;
  if (binT < 0) {
    for (int j = tid; j < M; j += 256) out[atomicAdd(&oc, 1)] = ci[j];
    __syncthreads();
    if (tid == 0 && M < 32) {
      float bd = 1e30f; int bx = 0x7FFFFFFF;
      for (int j = 0; j < M; ++j)
        if (cd[j] < bd || (cd[j] == bd && ci[j] < bx)) { bd = cd[j]; bx = ci[j]; }
      for (int j = M; j < 32; ++j) out[j] = bx;
    }
  } else {
    const int bt = binT, m = mlow;
    for (int j = tid; j < M; j += 256) {
      float dbj = (cd[j] > 0.0f) ? cd[j] : 0.0f;
      int bin = min(63, (int)(dbj * sc));
      if (bin < bt) out[atomicAdd(&oc, 1)] = ci[j];
      else if (bin == bt) {
        int r = 0; const float dj = cd[j]; const int ij = ci[j];
        for (int kk = 0; kk < M; ++kk) {
          float dbk = (cd[kk] > 0.0f) ? cd[kk] : 0.0f;
          if (min(63, (int)(dbk * sc)) == bt &&
              (cd[kk] < dj || (cd[kk] == dj && ci[kk] < ij))) ++r;
        }
        if (m + r < 32) out[m + r] = ci[j];
      }
    }
  }
}

// ---------------------------------------------------------------- grouped MLP + max  (out 128 ch)
// REVERTED to r13 (non-chunked, 4 rows/block): e-chunking doubled weight
// loads + barriers -- measured regression.
template <int FDIM>
__global__ __launch_bounds__(256) void k_group_mlp(
    const float* __restrict__ fea, const int* __restrict__ gidx,
    const float* __restrict__ newc, const float* __restrict__ candp,
    int mode, int ncand, float radius,
    const float* __restrict__ wp, float* __restrict__ outf) {
  constexpr int CP4 = FDIM + 4;     // padded cols (67->68, 131->132)
  constexpr int NC4 = CP4 / 4;
  __shared__ float4 g4[2][32][NC4];
  __shared__ int sidx[2][32];
  __shared__ float sq[2][3];
  __shared__ float pf[2][4][128];
  const int tid = threadIdx.x;
  const int rs = tid >> 7, tl = tid & 127;
  const int dt = tl & 31, et = tl >> 5;
  const int d0 = dt * 4, e0 = et * 8;
  const int row0 = blockIdx.x * 4;
  for (int rp = 0; rp < 4; rp += 2) {
    const int row = row0 + rp + rs;
    if (tl < 32) sidx[rs][tl] = gidx[(size_t)row * 32 + tl];
    if (tl < 3) sq[rs][tl] = newc[(size_t)row * 3 + tl];
    __syncthreads();
    const int bb2 = row / SS;
    const float* fb = fea + (size_t)bb2 * ncand * FDIM;
    const float* cb = (mode == 0) ? candp + (size_t)bb2 * 3 * NN
                                  : candp + (size_t)bb2 * SS * 3;
    float* gf = (float*)&g4[rs][0][0];
    for (int qq = tl; qq < 32 * CP4; qq += 128) {
      int e = qq / CP4, c = qq - e * CP4;
      int id = sidx[rs][e];
      float v;
      if (c < FDIM) v = fb[(size_t)id * FDIM + c];
      else if (c < FDIM + 3) {
        int comp = c - FDIM;
        float pcv = (mode == 0) ? cb[(size_t)comp * NN + id] : cb[(size_t)id * 3 + comp];
        v = (pcv - sq[rs][comp]) / radius;
      } else v = 0.0f;
      gf[qq] = v;
    }
    __syncthreads();
    float acc[4][8];
#pragma unroll
    for (int i = 0; i < 4; ++i)
#pragma unroll
      for (int j = 0; j < 8; ++j) acc[i][j] = 0.0f;
    const float4* w4 = (const float4*)wp;
    for (int c4 = 0; c4 < NC4; ++c4) {
      float4 wv[4], gv[8];
#pragma unroll
      for (int i = 0; i < 4; ++i) wv[i] = w4[(size_t)(d0 + i) * NC4 + c4];
#pragma unroll
      for (int j = 0; j < 8; ++j) gv[j] = g4[rs][e0 + j][c4];
#pragma unroll
      for (int i = 0; i < 4; ++i)
#pragma unroll
        for (int j = 0; j < 8; ++j) {
          acc[i][j] += wv[i].x * gv[j].x;
          acc[i][j] += wv[i].y * gv[j].y;
          acc[i][j] += wv[i].z * gv[j].z;
          acc[i][j] += wv[i].w * gv[j].w;
        }
    }
#pragma unroll
    for (int i = 0; i < 4; ++i) {
      float m = acc[i][0];
#pragma unroll
      for (int j = 1; j < 8; ++j) m = fmaxf(m, acc[i][j]);
      pf[rs][et][d0 + i] = m;
    }
    __syncthreads();
    {
      const int d = tid & 127, r2s = tid >> 7;
      const int rowW = row0 + rp + r2s;
      float m = fmaxf(fmaxf(pf[r2s][0][d], pf[r2s][1][d]),
                      fmaxf(pf[r2s][2][d], pf[r2s][3][d]));
      outf[(size_t)rowW * 128 + d] = fmaxf(m, 0.0f);
    }
    __syncthreads();
  }
}

// ---------------------------------------------------------------- dense GEMM: Out = relu(A(M,K) * W(N,K)^T [+ Id])
template <bool RESID>
__global__ __launch_bounds__(256) void k_dense(
    const float* __restrict__ A, const float* __restrict__ W,
    const float* __restrict__ Id, float* __restrict__ Out,
    int K, int Ntot) {
  __shared__ float4 sa[64][17], sb[64][17];
  const int m0 = blockIdx.x * 64, n0 = blockIdx.y * 64;
  const int tid = threadIdx.x;
  const int mt = tid & 15, nt = tid >> 4;
  float acc[4][4];
#pragma unroll
  for (int i = 0; i < 4; ++i)
#pragma unroll
    for (int j = 0; j < 4; ++j) acc[i][j] = 0.0f;
  for (int kc = 0; kc < K; kc += 64) {
    for (int q2 = tid; q2 < 2048; q2 += 256) {
      int half = q2 >> 10, qq = q2 & 1023;
      int r = qq >> 4, c = qq & 15;
      const float* src = half ? (W + (size_t)(n0 + r) * K + kc + c * 4)
                              : (A + (size_t)(m0 + r) * K + kc + c * 4);
      float4 v = *(const float4*)src;
      if (half) sb[r][c] = v; else sa[r][c] = v;
    }
    __syncthreads();
#pragma unroll
    for (int c = 0; c < 16; ++c) {
      const int ks = (c + mt + nt) & 15;  // swizzle to break LDS bank conflicts
      float4 av[4], bv[4];
#pragma unroll
      for (int i = 0; i < 4; ++i) av[i] = sa[mt * 4 + i][ks];
#pragma unroll
      for (int j = 0; j < 4; ++j) bv[j] = sb[nt * 4 + j][ks];
#pragma unroll
      for (int i = 0; i < 4; ++i)
#pragma unroll
        for (int j = 0; j < 4; ++j) {
          acc[i][j] += av[i].x * bv[j].x;
          acc[i][j] += av[i].y * bv[j].y;
          acc[i][j] += av[i].z * bv[j].z;
          acc[i][j] += av[i].w * bv[j].w;
        }
    }
    __syncthreads();
  }
#pragma unroll
  for (int i = 0; i < 4; ++i)
#pragma unroll
    for (int j = 0; j < 4; ++j) {
      size_t o = (size_t)(m0 + mt * 4 + i) * Ntot + n0 + nt * 4 + j;
      float v = acc[i][j];
      if (RESID) v += Id[o];
      Out[o] = fmaxf(v, 0.0f);
    }
}

// ---------------------------------------------------------------- pad weights rows to 4-aligned cols
__global__ void k_pad_w(const float* __restrict__ src, float* __restrict__ dst,
                        int rows, int cin, int cp4) {
  int t = blockIdx.x * 256 + threadIdx.x;
  if (t >= rows * cp4) return;
  int r = t / cp4, c = t - r * cp4;
  dst[t] = (c < cin) ? src[(size_t)r * cin + c] : 0.0f;
}

// ---------------------------------------------------------------- out1 transpose (B*S,128) -> (B,128,S)
__global__ void k_out1_t(const float* __restrict__ in, float* __restrict__ out) {
  __shared__ float tile[32][33];
  const int b = blockIdx.z;
  const int s0 = blockIdx.x * 32, d0 = blockIdx.y * 32;
  const int tx = threadIdx.x, ty = threadIdx.y;
#pragma unroll
  for (int i = 0; i < 32; i += 8)
    tile[ty + i][tx] = in[(size_t)(b * SS + s0 + ty + i) * 128 + d0 + tx];
  __syncthreads();
#pragma unroll
  for (int i = 0; i < 32; i += 8)
    out[(size_t)(b * 128 + d0 + ty + i) * SS + s0 + tx] = tile[tx][ty + i];
}

// ----------------------------------------------------------------
extern "C" void kernel_launch(void* const* d_in, const int* in_sizes, int n_in,
                              void* d_out, int out_size, void* d_ws, size_t ws_size,
                              hipStream_t stream) {
  const float* pc    = (const float*)d_in[0];
  const float* pfea  = (const float*)d_in[1];
  const float* w_sa  = (const float*)d_in[2];
  const float* w_la1 = (const float*)d_in[3];
  const float* w1_1  = (const float*)d_in[4];
  const float* w2_1  = (const float*)d_in[5];
  const float* w_la2 = (const float*)d_in[6];
  const float* w1_2  = (const float*)d_in[7];
  const float* w2_2  = (const float*)d_in[8];
  float* out0 = (float*)d_out;
  float* out1 = out0 + (size_t)BB * 3 * SS;

  char* wsp = (char*)d_ws;
  size_t off = 0;
  auto alloc = [&](size_t bytes) -> void* {
    void* p = wsp + off;
    off = (off + bytes + 255) & ~(size_t)255;
    return p;
  };
  float* hbuf = (float*)alloc((size_t)BB * SS * HHV * 4);  // 16 MB; also aliased as feaT (disjoint in time)
  float* feaT = hbuf;                                      // 8 MB needed, used only before hbuf
  int*   fpsi = (int*)alloc((size_t)BB * SS * 4);
  float* ncoor = (float*)alloc((size_t)BB * SS * 3 * 4);
  int*   gi = (int*)alloc((size_t)BB * SS * GG * 4);
  float* fa = (float*)alloc((size_t)BB * SS * C2V * 4);
  float* fb = (float*)alloc((size_t)BB * SS * C2V * 4);
  float* wsap = (float*)alloc(128 * 68 * 4);
  float* wla1p = (float*)alloc(128 * 132 * 4);
  float* wla2p = (float*)alloc(128 * 132 * 4);

  k_pad_w<<<dim3((128 * 68 + 255) / 256), dim3(256), 0, stream>>>(w_sa, wsap, 128, 67, 68);
  k_pad_w<<<dim3((128 * 132 + 255) / 256), dim3(256), 0, stream>>>(w_la1, wla1p, 128, 131, 132);
  k_pad_w<<<dim3((128 * 132 + 255) / 256), dim3(256), 0, stream>>>(w_la2, wla2p, 128, 131, 132);

  k_transpose_fea<<<dim3(NN / 32, CC / 32, BB), dim3(32, 8), 0, stream>>>(pfea, feaT);
  k_fps<<<dim3(BB), dim3(512), 0, stream>>>(pc, fpsi);
  k_gather<<<dim3((BB * SS + 255) / 256), dim3(256), 0, stream>>>(pc, fpsi, ncoor, out0);

  // stage 1: group among original N points, r=0.2
  k_knn<<<dim3(BB * SS), dim3(256), 0, stream>>>(pc, ncoor, 0, NN, 0.04f, gi);
  k_group_mlp<64><<<dim3(BB * SS / 4), dim3(256), 0, stream>>>(feaT, gi, ncoor, pc, 0, NN, 0.2f, wsap, fa);

  // shared grouping for both inv-res blocks (same points, same radius 0.4)
  k_knn<<<dim3(BB * SS), dim3(256), 0, stream>>>(ncoor, ncoor, 1, SS, 0.16f, gi);

  // inv-res block 1
  k_group_mlp<128><<<dim3(BB * SS / 4), dim3(256), 0, stream>>>(fa, gi, ncoor, ncoor, 1, SS, 0.4f, wla1p, fb);
  k_dense<false><<<dim3(128, 8), dim3(256), 0, stream>>>(fb, w1_1, nullptr, hbuf, 128, 512);
  k_dense<true><<<dim3(128, 2), dim3(256), 0, stream>>>(hbuf, w2_1, fa, fb, 512, 128);

  // inv-res block 2
  k_group_mlp<128><<<dim3(BB * SS / 4), dim3(256), 0, stream>>>(fb, gi, ncoor, ncoor, 1, SS, 0.4f, wla2p, fa);
  k_dense<false><<<dim3(128, 8), dim3(256), 0, stream>>>(fa, w1_2, nullptr, hbuf, 128, 512);
  k_dense<true><<<dim3(128, 2), dim3(256), 0, stream>>>(hbuf, w2_2, fb, fa, 512, 128);

  k_out1_t<<<dim3(SS / 32, 128 / 32, BB), dim3(32, 8), 0, stream>>>(fa, out1);
}